// Round 10
// baseline (128.211 us; speedup 1.0000x reference)
//
#include <hip/hip_runtime.h>

#define NN 100000
#define EE 3200000
#define FIN 128
#define HID 16
#define NC 8

#define CHUNK 6250
#define NBLK 512                           // CHUNK*NBLK == EE exactly
#define BW 256                             // nodes per bucket
#define NBUK ((NN + BW - 1) / BW)          // 391
#define EPT 7                              // ceil(CHUNK/1024)
#define CAP 9216                           // bucket slab capacity (mean 8184, sigma 90 -> 11 sigma)
#define BEPT 9                             // ceil(CAP/1024)

// pack two floats into bf16x2 (round-to-nearest-even)
__device__ __forceinline__ unsigned bf16pair(float a, float b) {
    unsigned ua = __float_as_uint(a), ub = __float_as_uint(b);
    ua = ua + 0x7fffu + ((ua >> 16) & 1u);
    ub = ub + 0x7fffu + ((ub >> 16) & 1u);
    return (ua >> 16) | (ub & 0xffff0000u);
}
__device__ __forceinline__ float bflo(unsigned v) { return __uint_as_float(v << 16); }
__device__ __forceinline__ float bfhi(unsigned v) { return __uint_as_float(v & 0xffff0000u); }

// ---------------- zero the bucket cursors ----------------
__global__ __launch_bounds__(512) void k_zero_cursor(unsigned* __restrict__ cursor) {
    int t = threadIdx.x;
    if (t < NBUK) cursor[t] = 0u;
}

// ---------------- pass 1: LDS chunk sort + ticket slab allocation + coalesced writeout ----
// bins_pk[slot] = src | (dst & 255) << 17   (src < 2^17, dl < 2^8)
__global__ __launch_bounds__(1024) void k_binscatter(const int* __restrict__ row,
                                                     const int* __restrict__ col,
                                                     unsigned* __restrict__ cursor,
                                                     unsigned* __restrict__ bins_pk) {
    __shared__ unsigned s_cnt[NBUK];     // raw counts -> (after scan) inclusive
    __shared__ unsigned s_start[NBUK];   // exclusive start in stg
    __shared__ unsigned s_off[NBUK];     // running rank
    __shared__ unsigned s_gb[NBUK];      // ticket base within bucket slab
    __shared__ unsigned stg[CHUNK];      // 25 KB
    int t = threadIdx.x;
    for (int i = t; i < NBUK; i += 1024) s_cnt[i] = 0u;
    __syncthreads();
    int base = blockIdx.x * CHUNK;
    unsigned val[EPT];
    unsigned short bk[EPT];
    #pragma unroll
    for (int k = 0; k < EPT; ++k) {
        int i = t + k * 1024;
        if (i < CHUNK) {
            int s = row[base + i];
            int d = col[base + i];
            unsigned b = (unsigned)d >> 8;
            val[k] = (unsigned)s | ((unsigned)(d & 255) << 17);
            bk[k] = (unsigned short)b;
            atomicAdd(&s_cnt[b], 1u);
        }
    }
    __syncthreads();
    // ticket: reserve a contiguous run in each bucket's slab (s_cnt still raw)
    for (int i = t; i < NBUK; i += 1024)
        s_gb[i] = atomicAdd(&cursor[i], s_cnt[i]);
    __syncthreads();
    // inclusive scan s_cnt over NBUK entries
    for (int off = 1; off < NBUK; off <<= 1) {
        unsigned v = 0u;
        if (t < NBUK && t >= off) v = s_cnt[t - off];
        __syncthreads();
        if (t < NBUK) s_cnt[t] += v;
        __syncthreads();
    }
    if (t < NBUK) {
        unsigned st = (t == 0) ? 0u : s_cnt[t - 1];
        s_start[t] = st;
        s_off[t] = st;
    }
    __syncthreads();
    // rank-scatter into LDS stage
    #pragma unroll
    for (int k = 0; k < EPT; ++k) {
        int i = t + k * 1024;
        if (i < CHUNK) {
            unsigned b = bk[k];
            unsigned r = atomicAdd(&s_off[b], 1u);
            stg[r] = val[k];
        }
    }
    __syncthreads();
    // per-bucket segment writeout: wave w handles buckets w, w+16, ...
    int w = t >> 6, lane = t & 63;
    for (int b = w; b < NBUK; b += 16) {
        unsigned st = s_start[b];
        unsigned en = s_cnt[b];          // inclusive = segment end
        unsigned dst = (unsigned)b * CAP + s_gb[b];
        for (unsigned i = st + lane; i < en; i += 64)
            bins_pk[dst + (i - st)] = stg[i];
    }
}

// ---------------- pass 2: per-bucket CSR build (slab in, padded slab out) ----------------
__global__ __launch_bounds__(1024) void k_build(const unsigned* __restrict__ bins_pk,
                                                const unsigned* __restrict__ cursor,
                                                uint2* __restrict__ row_se,
                                                float* __restrict__ dinv,
                                                unsigned* __restrict__ srcsort) {
    __shared__ unsigned cnt[BW];       // per-node count -> inclusive scan
    __shared__ unsigned offn[BW];      // running rank
    __shared__ unsigned stg[CAP];      // 36 KB
    int t = threadIdx.x, b = blockIdx.x;
    if (t < BW) cnt[t] = 0u;
    __syncthreads();
    unsigned m = cursor[b];
    unsigned base = (unsigned)b * CAP;
    unsigned val[BEPT];
    unsigned char dl[BEPT];
    #pragma unroll
    for (int k = 0; k < BEPT; ++k) {
        unsigned i = t + k * 1024u;
        if (i < m) {
            unsigned w = bins_pk[base + i];
            val[k] = w & 0x1FFFFu;
            dl[k] = (unsigned char)(w >> 17);
            atomicAdd(&cnt[dl[k]], 1u);
        }
    }
    __syncthreads();
    // inclusive scan over BW entries
    for (int off = 1; off < BW; off <<= 1) {
        unsigned v = 0u;
        if (t < BW && t >= off) v = cnt[t - off];
        __syncthreads();
        if (t < BW) cnt[t] += v;
        __syncthreads();
    }
    if (t < BW) {
        unsigned st = (t == 0) ? 0u : cnt[t - 1];
        offn[t] = st;
        int node = b * BW + t;
        if (node < NN) {
            row_se[node] = uint2{base + st, base + cnt[t]};
            dinv[node] = rsqrtf(1.0f + (float)(cnt[t] - st));
        }
    }
    __syncthreads();
    // rank-scatter into LDS stage (in-bucket final order)
    #pragma unroll
    for (int k = 0; k < BEPT; ++k) {
        unsigned i = t + k * 1024u;
        if (i < m) {
            unsigned r = atomicAdd(&offn[dl[k]], 1u);
            stg[r] = val[k];
        }
    }
    __syncthreads();
    // perfectly sequential writeout
    for (unsigned i = t; i < m; i += 1024u)
        srcsort[base + i] = stg[i];
}

// ---------------- layer 1 transform: hs1b = bf16((x @ W1) * dinv) ----------------
__global__ __launch_bounds__(256) void k_gemm1(const float* __restrict__ x,
                                               const float* __restrict__ W1,
                                               const float* __restrict__ dinv,
                                               unsigned* __restrict__ hs1b) {
    __shared__ float w1s[FIN * HID];
    __shared__ float xs[64 * 132];
    int t = threadIdx.x;
    int r0 = blockIdx.x * 64;
    for (int i = t; i < FIN * HID; i += 256) w1s[i] = W1[i];
    int maxr = NN - r0; if (maxr > 64) maxr = 64;
    const float4* x4 = reinterpret_cast<const float4*>(x + (size_t)r0 * FIN);
    #pragma unroll
    for (int i = 0; i < 8; ++i) {
        int fi = t + i * 256;
        int f = fi * 4;
        int r = f >> 7, k = f & 127;
        if (r < maxr) {
            float4 v = x4[fi];
            *reinterpret_cast<float4*>(&xs[r * 132 + k]) = v;
        }
    }
    __syncthreads();
    int r = t >> 2;
    int cg = (t & 3) * 4;
    if (r < maxr) {
        float4 acc = {0.f, 0.f, 0.f, 0.f};
        const float* xr = &xs[r * 132];
        #pragma unroll 4
        for (int k = 0; k < FIN; ++k) {
            float xv = xr[k];
            const float4 w = *reinterpret_cast<const float4*>(&w1s[k * HID + cg]);
            acc.x += xv * w.x; acc.y += xv * w.y; acc.z += xv * w.z; acc.w += xv * w.w;
        }
        int rr = r0 + r;
        float di = dinv[rr];
        uint2 pk;
        pk.x = bf16pair(acc.x * di, acc.y * di);
        pk.y = bf16pair(acc.z * di, acc.w * di);
        *reinterpret_cast<uint2*>(&hs1b[(rr << 3) + (cg >> 1)]) = pk;
    }
}

// ---------------- layer 1 aggregate (uint2 gather) + finalize + W2 ----------------
// 256 threads = 64 nodes x 4 lanes (each lane: 4 channels = one uint2)
__global__ __launch_bounds__(256) void k_l1(const uint2* __restrict__ row_se,
                                            const unsigned* __restrict__ srcsort,
                                            const uint2* __restrict__ hs1b2,
                                            const float* __restrict__ dinv,
                                            const float* __restrict__ W2,
                                            const float* __restrict__ b1,
                                            unsigned* __restrict__ hs2b) {
    __shared__ float htile[64 * 17];
    __shared__ float w2s[HID * NC];
    int t = threadIdx.x;
    if (t < HID * NC) w2s[t] = W2[t];
    int g = t >> 2;          // node in block 0..63
    int c4 = t & 3;          // uint2 index (4 channels)
    int n = blockIdx.x * 64 + g;     // grid 1563 -> guard
    if (n < NN) {
        uint2 se = row_se[n];
        unsigned e = se.x, e1 = se.y;
        float a0 = 0.f, a1 = 0.f, a2 = 0.f, a3 = 0.f;
        for (; e + 3 < e1; e += 4) {
            int s0 = srcsort[e];
            int s1 = srcsort[e + 1];
            int s2 = srcsort[e + 2];
            int s3 = srcsort[e + 3];
            uint2 v0 = hs1b2[(s0 << 2) + c4];
            uint2 v1 = hs1b2[(s1 << 2) + c4];
            uint2 v2 = hs1b2[(s2 << 2) + c4];
            uint2 v3 = hs1b2[(s3 << 2) + c4];
            a0 += bflo(v0.x) + bflo(v1.x) + bflo(v2.x) + bflo(v3.x);
            a1 += bfhi(v0.x) + bfhi(v1.x) + bfhi(v2.x) + bfhi(v3.x);
            a2 += bflo(v0.y) + bflo(v1.y) + bflo(v2.y) + bflo(v3.y);
            a3 += bfhi(v0.y) + bfhi(v1.y) + bfhi(v2.y) + bfhi(v3.y);
        }
        for (; e < e1; ++e) {
            uint2 v = hs1b2[((int)srcsort[e] << 2) + c4];
            a0 += bflo(v.x); a1 += bfhi(v.x); a2 += bflo(v.y); a3 += bfhi(v.y);
        }
        {   // self-loop
            uint2 v = hs1b2[(n << 2) + c4];
            a0 += bflo(v.x); a1 += bfhi(v.x); a2 += bflo(v.y); a3 += bfhi(v.y);
        }
        float di = dinv[n];
        int c = c4 * 4;
        htile[g * 17 + c]     = fmaxf(a0 * di + b1[c], 0.f);
        htile[g * 17 + c + 1] = fmaxf(a1 * di + b1[c + 1], 0.f);
        htile[g * 17 + c + 2] = fmaxf(a2 * di + b1[c + 2], 0.f);
        htile[g * 17 + c + 3] = fmaxf(a3 * di + b1[c + 3], 0.f);
    }
    __syncthreads();
    {
        int n2 = t >> 2, j2 = t & 3;     // node 0..63, output pair 0..3
        int node2 = blockIdx.x * 64 + n2;
        if (node2 < NN) {
            const float* hr = &htile[n2 * 17];
            float oa = 0.f, ob = 0.f;
            #pragma unroll
            for (int k = 0; k < HID; ++k) {
                float hv = hr[k];
                oa += hv * w2s[k * NC + 2 * j2];
                ob += hv * w2s[k * NC + 2 * j2 + 1];
            }
            float d2 = dinv[node2];
            hs2b[(node2 << 2) + j2] = bf16pair(oa * d2, ob * d2);
        }
    }
}

// ---------------- layer 2 aggregate (uint2 gather) + finalize + log_softmax ----------------
// 256 threads = 128 nodes x 2 lanes (each lane: 4 channels = one uint2)
__global__ __launch_bounds__(256) void k_l2(const uint2* __restrict__ row_se,
                                            const unsigned* __restrict__ srcsort,
                                            const uint2* __restrict__ hs2b2,
                                            const float* __restrict__ dinv,
                                            const float* __restrict__ b2,
                                            float* __restrict__ out) {
    int t = threadIdx.x;
    int g = t >> 1;          // node in block 0..127
    int p = t & 1;           // uint2 index (channels 4p..4p+3)
    int n = blockIdx.x * 128 + g;
    if (n >= NN) return;
    uint2 se = row_se[n];
    unsigned e = se.x, e1 = se.y;
    float a0 = 0.f, a1 = 0.f, a2 = 0.f, a3 = 0.f;
    for (; e + 3 < e1; e += 4) {
        int s0 = srcsort[e];
        int s1 = srcsort[e + 1];
        int s2 = srcsort[e + 2];
        int s3 = srcsort[e + 3];
        uint2 v0 = hs2b2[(s0 << 1) + p];
        uint2 v1 = hs2b2[(s1 << 1) + p];
        uint2 v2 = hs2b2[(s2 << 1) + p];
        uint2 v3 = hs2b2[(s3 << 1) + p];
        a0 += bflo(v0.x) + bflo(v1.x) + bflo(v2.x) + bflo(v3.x);
        a1 += bfhi(v0.x) + bfhi(v1.x) + bfhi(v2.x) + bfhi(v3.x);
        a2 += bflo(v0.y) + bflo(v1.y) + bflo(v2.y) + bflo(v3.y);
        a3 += bfhi(v0.y) + bfhi(v1.y) + bfhi(v2.y) + bfhi(v3.y);
    }
    for (; e < e1; ++e) {
        uint2 v = hs2b2[((int)srcsort[e] << 1) + p];
        a0 += bflo(v.x); a1 += bfhi(v.x); a2 += bflo(v.y); a3 += bfhi(v.y);
    }
    {   // self-loop
        uint2 v = hs2b2[(n << 1) + p];
        a0 += bflo(v.x); a1 += bfhi(v.x); a2 += bflo(v.y); a3 += bfhi(v.y);
    }
    float di = dinv[n];
    int c = p * 4;
    float v0 = a0 * di + b2[c];
    float v1 = a1 * di + b2[c + 1];
    float v2 = a2 * di + b2[c + 2];
    float v3 = a3 * di + b2[c + 3];
    float m = fmaxf(fmaxf(v0, v1), fmaxf(v2, v3));
    m = fmaxf(m, __shfl_xor(m, 1, 2));
    float s = expf(v0 - m) + expf(v1 - m) + expf(v2 - m) + expf(v3 - m);
    s += __shfl_xor(s, 1, 2);
    float ls = logf(s);
    float4 o = {v0 - m - ls, v1 - m - ls, v2 - m - ls, v3 - m - ls};
    *reinterpret_cast<float4*>(&out[(n << 3) + c]) = o;
}

extern "C" void kernel_launch(void* const* d_in, const int* in_sizes, int n_in,
                              void* d_out, int out_size, void* d_ws, size_t ws_size,
                              hipStream_t stream) {
    const float* x   = (const float*)d_in[0];
    const int*   ei  = (const int*)d_in[1];
    const float* W1  = (const float*)d_in[2];
    const float* b1  = (const float*)d_in[3];
    const float* W2  = (const float*)d_in[4];
    const float* b2  = (const float*)d_in[5];
    float* out = (float*)d_out;

    const int* row = ei;
    const int* col = ei + EE;

    // ws layout (4-byte units)
    float*    ws      = (float*)d_ws;
    float*    dinv    = ws;                                    // NN
    unsigned* hs1b    = (unsigned*)(dinv + NN);                // NN*8 (bf16 x16)
    unsigned* hs2b    = hs1b + (size_t)NN * 8;                 // NN*4 (bf16 x8)
    uint2*    row_se  = (uint2*)(hs2b + (size_t)NN * 4);       // NN uint2
    unsigned* cursor  = (unsigned*)(row_se + NN);              // NBUK
    unsigned* bins_pk = cursor + NBUK;                         // NBUK*CAP slab
    unsigned* srcsort = bins_pk + (size_t)NBUK * CAP;          // NBUK*CAP slab

    k_zero_cursor <<<1, 512, 0, stream>>>(cursor);
    k_binscatter  <<<NBLK, 1024, 0, stream>>>(row, col, cursor, bins_pk);
    k_build       <<<NBUK, 1024, 0, stream>>>(bins_pk, cursor, row_se, dinv, srcsort);
    k_gemm1       <<<(NN + 63) / 64, 256, 0, stream>>>(x, W1, dinv, hs1b);
    k_l1          <<<(NN + 63) / 64, 256, 0, stream>>>(row_se, srcsort, (const uint2*)hs1b, dinv, W2, b1, hs2b);
    k_l2          <<<(NN + 127) / 128, 256, 0, stream>>>(row_se, srcsort, (const uint2*)hs2b, dinv, b2, out);
}

// Round 11
// 114.524 us; speedup vs baseline: 1.1195x; 1.1195x over previous
//
#include <hip/hip_runtime.h>

#define NN 100000
#define EE 3200000
#define FIN 128
#define HID 16
#define NC 8

#define CHUNK 12500
#define NBLK 256                           // CHUNK*NBLK == EE exactly
#define BW 256                             // nodes per bucket
#define NBUK ((NN + BW - 1) / BW)          // 391
#define EPT 13                             // ceil(CHUNK/1024)
#define CAP 9216                           // bucket slab capacity (mean 8184, sigma 90 -> 11 sigma)
#define BEPT 9                             // ceil(CAP/1024)

// pack two floats into bf16x2 (round-to-nearest-even)
__device__ __forceinline__ unsigned bf16pair(float a, float b) {
    unsigned ua = __float_as_uint(a), ub = __float_as_uint(b);
    ua = ua + 0x7fffu + ((ua >> 16) & 1u);
    ub = ub + 0x7fffu + ((ub >> 16) & 1u);
    return (ua >> 16) | (ub & 0xffff0000u);
}

// ---------------- pass 1: LDS chunk sort + ticket slab allocation + coalesced writeout ----
// bins_pk[slot] = src | (dst & 255) << 17   (src < 2^17, dl < 2^8)
// LDS: 50000(stg) + 25000(bktid) + 3*1564 = 79,692 B  -> 2 blocks/CU (32 waves)
__global__ __launch_bounds__(1024) void k_binscatter(const int* __restrict__ row,
                                                     const int* __restrict__ col,
                                                     unsigned* __restrict__ cursor,
                                                     unsigned* __restrict__ bins_pk) {
    __shared__ unsigned s_cnt[NBUK];     // raw counts -> (after scan) inclusive
    __shared__ unsigned s_off[NBUK];     // running rank (starts at exclusive start)
    __shared__ unsigned s_gb[NBUK];      // ticket -> folded dest bias (b*CAP + gb - start)
    __shared__ unsigned stg[CHUNK];                 // 50 KB
    __shared__ unsigned short bktid[CHUNK];         // 25 KB
    int t = threadIdx.x;
    for (int i = t; i < NBUK; i += 1024) s_cnt[i] = 0u;
    __syncthreads();
    int base = blockIdx.x * CHUNK;
    unsigned val[EPT];
    unsigned short bk[EPT];
    #pragma unroll
    for (int k = 0; k < EPT; ++k) {
        int i = t + k * 1024;
        if (i < CHUNK) {
            int s = row[base + i];
            int d = col[base + i];
            unsigned b = (unsigned)d >> 8;
            val[k] = (unsigned)s | ((unsigned)(d & 255) << 17);
            bk[k] = (unsigned short)b;
            atomicAdd(&s_cnt[b], 1u);
        }
    }
    __syncthreads();
    // ticket: reserve a contiguous run in each bucket's slab (s_cnt still raw)
    for (int i = t; i < NBUK; i += 1024)
        s_gb[i] = atomicAdd(&cursor[i], s_cnt[i]);
    __syncthreads();
    // inclusive scan s_cnt over NBUK entries
    for (int off = 1; off < NBUK; off <<= 1) {
        unsigned v = 0u;
        if (t < NBUK && t >= off) v = s_cnt[t - off];
        __syncthreads();
        if (t < NBUK) s_cnt[t] += v;
        __syncthreads();
    }
    if (t < NBUK) {
        unsigned st = (t == 0) ? 0u : s_cnt[t - 1];
        s_off[t] = st;
        // fold dest base: modular arithmetic keeps final (bias + i) exact
        s_gb[t] = (unsigned)t * CAP + s_gb[t] - st;
    }
    __syncthreads();
    // rank-scatter into LDS stage
    #pragma unroll
    for (int k = 0; k < EPT; ++k) {
        int i = t + k * 1024;
        if (i < CHUNK) {
            unsigned b = bk[k];
            unsigned r = atomicAdd(&s_off[b], 1u);
            stg[r] = val[k];
            bktid[r] = (unsigned short)b;
        }
    }
    __syncthreads();
    // coalesced writeout into bucket slabs
    for (int i = t; i < CHUNK; i += 1024) {
        unsigned b = bktid[i];
        bins_pk[s_gb[b] + (unsigned)i] = stg[i];
    }
}

// ---------------- pass 2: per-bucket CSR build (slab in, padded slab out) ----------------
__global__ __launch_bounds__(1024) void k_build(const unsigned* __restrict__ bins_pk,
                                                const unsigned* __restrict__ cursor,
                                                uint2* __restrict__ row_se,
                                                float* __restrict__ dinv,
                                                unsigned* __restrict__ srcsort) {
    __shared__ unsigned cnt[BW];       // per-node count -> inclusive scan
    __shared__ unsigned offn[BW];      // running rank
    __shared__ unsigned stg[CAP];      // 36 KB
    int t = threadIdx.x, b = blockIdx.x;
    if (t < BW) cnt[t] = 0u;
    __syncthreads();
    unsigned m = cursor[b];
    unsigned base = (unsigned)b * CAP;
    unsigned val[BEPT];
    unsigned char dl[BEPT];
    #pragma unroll
    for (int k = 0; k < BEPT; ++k) {
        unsigned i = t + k * 1024u;
        if (i < m) {
            unsigned w = bins_pk[base + i];
            val[k] = w & 0x1FFFFu;
            dl[k] = (unsigned char)(w >> 17);
            atomicAdd(&cnt[dl[k]], 1u);
        }
    }
    __syncthreads();
    // inclusive scan over BW entries
    for (int off = 1; off < BW; off <<= 1) {
        unsigned v = 0u;
        if (t < BW && t >= off) v = cnt[t - off];
        __syncthreads();
        if (t < BW) cnt[t] += v;
        __syncthreads();
    }
    if (t < BW) {
        unsigned st = (t == 0) ? 0u : cnt[t - 1];
        offn[t] = st;
        int node = b * BW + t;
        if (node < NN) {
            row_se[node] = uint2{base + st, base + cnt[t]};
            dinv[node] = rsqrtf(1.0f + (float)(cnt[t] - st));
        }
    }
    __syncthreads();
    // rank-scatter into LDS stage (in-bucket final order)
    #pragma unroll
    for (int k = 0; k < BEPT; ++k) {
        unsigned i = t + k * 1024u;
        if (i < m) {
            unsigned r = atomicAdd(&offn[dl[k]], 1u);
            stg[r] = val[k];
        }
    }
    __syncthreads();
    // perfectly sequential writeout
    for (unsigned i = t; i < m; i += 1024u)
        srcsort[base + i] = stg[i];
}

// ---------------- layer 1 transform: hs1b = bf16((x @ W1) * dinv) ----------------
__global__ __launch_bounds__(256) void k_gemm1(const float* __restrict__ x,
                                               const float* __restrict__ W1,
                                               const float* __restrict__ dinv,
                                               unsigned* __restrict__ hs1b) {
    __shared__ float w1s[FIN * HID];
    __shared__ float xs[64 * 132];
    int t = threadIdx.x;
    int r0 = blockIdx.x * 64;
    for (int i = t; i < FIN * HID; i += 256) w1s[i] = W1[i];
    int maxr = NN - r0; if (maxr > 64) maxr = 64;
    const float4* x4 = reinterpret_cast<const float4*>(x + (size_t)r0 * FIN);
    #pragma unroll
    for (int i = 0; i < 8; ++i) {
        int fi = t + i * 256;
        int f = fi * 4;
        int r = f >> 7, k = f & 127;
        if (r < maxr) {
            float4 v = x4[fi];
            *reinterpret_cast<float4*>(&xs[r * 132 + k]) = v;
        }
    }
    __syncthreads();
    int r = t >> 2;
    int cg = (t & 3) * 4;
    if (r < maxr) {
        float4 acc = {0.f, 0.f, 0.f, 0.f};
        const float* xr = &xs[r * 132];
        #pragma unroll 4
        for (int k = 0; k < FIN; ++k) {
            float xv = xr[k];
            const float4 w = *reinterpret_cast<const float4*>(&w1s[k * HID + cg]);
            acc.x += xv * w.x; acc.y += xv * w.y; acc.z += xv * w.z; acc.w += xv * w.w;
        }
        int rr = r0 + r;
        float di = dinv[rr];
        uint2 pk;
        pk.x = bf16pair(acc.x * di, acc.y * di);
        pk.y = bf16pair(acc.z * di, acc.w * di);
        *reinterpret_cast<uint2*>(&hs1b[(rr << 3) + (cg >> 1)]) = pk;
    }
}

// ---------------- layer 1 aggregate (bf16 gather) + finalize + W2 ----------------
// 256 threads = 32 nodes x 8 lanes (each lane: 2 channels packed)
__global__ __launch_bounds__(256) void k_l1(const uint2* __restrict__ row_se,
                                            const unsigned* __restrict__ srcsort,
                                            const unsigned* __restrict__ hs1b,
                                            const float* __restrict__ dinv,
                                            const float* __restrict__ W2,
                                            const float* __restrict__ b1,
                                            unsigned* __restrict__ hs2b) {
    __shared__ float htile[32 * 17];
    __shared__ float w2s[HID * NC];
    int t = threadIdx.x;
    if (t < HID * NC) w2s[t] = W2[t];
    int g = t >> 3;          // node in block 0..31
    int c2 = t & 7;          // uint index (2 channels)
    int n = blockIdx.x * 32 + g;   // grid 3125*32 == NN
    uint2 se = row_se[n];
    unsigned e = se.x, e1 = se.y;
    float a0 = 0.f, a1 = 0.f;
    for (; e + 3 < e1; e += 4) {
        int s0 = srcsort[e];
        int s1 = srcsort[e + 1];
        int s2 = srcsort[e + 2];
        int s3 = srcsort[e + 3];
        unsigned v0 = hs1b[(s0 << 3) + c2];
        unsigned v1 = hs1b[(s1 << 3) + c2];
        unsigned v2 = hs1b[(s2 << 3) + c2];
        unsigned v3 = hs1b[(s3 << 3) + c2];
        a0 += __uint_as_float(v0 << 16) + __uint_as_float(v1 << 16)
            + __uint_as_float(v2 << 16) + __uint_as_float(v3 << 16);
        a1 += __uint_as_float(v0 & 0xffff0000u) + __uint_as_float(v1 & 0xffff0000u)
            + __uint_as_float(v2 & 0xffff0000u) + __uint_as_float(v3 & 0xffff0000u);
    }
    for (; e < e1; ++e) {
        unsigned v = hs1b[((int)srcsort[e] << 3) + c2];
        a0 += __uint_as_float(v << 16);
        a1 += __uint_as_float(v & 0xffff0000u);
    }
    {   // self-loop
        unsigned v = hs1b[(n << 3) + c2];
        a0 += __uint_as_float(v << 16);
        a1 += __uint_as_float(v & 0xffff0000u);
    }
    float di = dinv[n];
    int c = c2 * 2;
    htile[g * 17 + c]     = fmaxf(a0 * di + b1[c], 0.f);
    htile[g * 17 + c + 1] = fmaxf(a1 * di + b1[c + 1], 0.f);
    __syncthreads();
    if (t < 128) {
        int n2 = t >> 2, j2 = t & 3;     // node 0..31, output pair 0..3
        const float* hr = &htile[n2 * 17];
        float oa = 0.f, ob = 0.f;
        #pragma unroll
        for (int k = 0; k < HID; ++k) {
            float hv = hr[k];
            oa += hv * w2s[k * NC + 2 * j2];
            ob += hv * w2s[k * NC + 2 * j2 + 1];
        }
        int node2 = blockIdx.x * 32 + n2;
        float d2 = dinv[node2];
        hs2b[(node2 << 2) + j2] = bf16pair(oa * d2, ob * d2);
    }
}

// ---------------- layer 2 aggregate (bf16 gather) + finalize + log_softmax ----------------
// 256 threads = 64 nodes x 4 lanes (each lane: 2 channels packed)
__global__ __launch_bounds__(256) void k_l2(const uint2* __restrict__ row_se,
                                            const unsigned* __restrict__ srcsort,
                                            const unsigned* __restrict__ hs2b,
                                            const float* __restrict__ dinv,
                                            const float* __restrict__ b2,
                                            float* __restrict__ out) {
    int t = threadIdx.x;
    int g = t >> 2;          // node in block 0..63
    int c2 = t & 3;          // uint index (2 channels)
    int n = blockIdx.x * 64 + g;
    if (n >= NN) return;
    uint2 se = row_se[n];
    unsigned e = se.x, e1 = se.y;
    float a0 = 0.f, a1 = 0.f;
    for (; e + 3 < e1; e += 4) {
        int s0 = srcsort[e];
        int s1 = srcsort[e + 1];
        int s2 = srcsort[e + 2];
        int s3 = srcsort[e + 3];
        unsigned v0 = hs2b[(s0 << 2) + c2];
        unsigned v1 = hs2b[(s1 << 2) + c2];
        unsigned v2 = hs2b[(s2 << 2) + c2];
        unsigned v3 = hs2b[(s3 << 2) + c2];
        a0 += __uint_as_float(v0 << 16) + __uint_as_float(v1 << 16)
            + __uint_as_float(v2 << 16) + __uint_as_float(v3 << 16);
        a1 += __uint_as_float(v0 & 0xffff0000u) + __uint_as_float(v1 & 0xffff0000u)
            + __uint_as_float(v2 & 0xffff0000u) + __uint_as_float(v3 & 0xffff0000u);
    }
    for (; e < e1; ++e) {
        unsigned v = hs2b[((int)srcsort[e] << 2) + c2];
        a0 += __uint_as_float(v << 16);
        a1 += __uint_as_float(v & 0xffff0000u);
    }
    {   // self-loop
        unsigned v = hs2b[(n << 2) + c2];
        a0 += __uint_as_float(v << 16);
        a1 += __uint_as_float(v & 0xffff0000u);
    }
    float di = dinv[n];
    int c = c2 * 2;
    float v0 = a0 * di + b2[c];
    float v1 = a1 * di + b2[c + 1];
    float m = fmaxf(v0, v1);
    m = fmaxf(m, __shfl_xor(m, 1, 4));
    m = fmaxf(m, __shfl_xor(m, 2, 4));
    float s = expf(v0 - m) + expf(v1 - m);
    s += __shfl_xor(s, 1, 4);
    s += __shfl_xor(s, 2, 4);
    float ls = logf(s);
    float2 o = {v0 - m - ls, v1 - m - ls};
    *reinterpret_cast<float2*>(&out[(n << 3) + c]) = o;
}

extern "C" void kernel_launch(void* const* d_in, const int* in_sizes, int n_in,
                              void* d_out, int out_size, void* d_ws, size_t ws_size,
                              hipStream_t stream) {
    const float* x   = (const float*)d_in[0];
    const int*   ei  = (const int*)d_in[1];
    const float* W1  = (const float*)d_in[2];
    const float* b1  = (const float*)d_in[3];
    const float* W2  = (const float*)d_in[4];
    const float* b2  = (const float*)d_in[5];
    float* out = (float*)d_out;

    const int* row = ei;
    const int* col = ei + EE;

    // ws layout (4-byte units)
    float*    ws      = (float*)d_ws;
    float*    dinv    = ws;                                    // NN
    unsigned* hs1b    = (unsigned*)(dinv + NN);                // NN*8 (bf16 x16)
    unsigned* hs2b    = hs1b + (size_t)NN * 8;                 // NN*4 (bf16 x8)
    uint2*    row_se  = (uint2*)(hs2b + (size_t)NN * 4);       // NN uint2
    unsigned* cursor  = (unsigned*)(row_se + NN);              // NBUK
    unsigned* bins_pk = cursor + NBUK;                         // NBUK*CAP slab
    unsigned* srcsort = bins_pk + (size_t)NBUK * CAP;          // NBUK*CAP slab

    hipMemsetAsync(cursor, 0, NBUK * sizeof(unsigned), stream);
    k_binscatter  <<<NBLK, 1024, 0, stream>>>(row, col, cursor, bins_pk);
    k_build       <<<NBUK, 1024, 0, stream>>>(bins_pk, cursor, row_se, dinv, srcsort);
    k_gemm1       <<<(NN + 63) / 64, 256, 0, stream>>>(x, W1, dinv, hs1b);
    k_l1          <<<NN / 32, 256, 0, stream>>>(row_se, srcsort, hs1b, dinv, W2, b1, hs2b);
    k_l2          <<<(NN + 63) / 64, 256, 0, stream>>>(row_se, srcsort, hs2b, dinv, b2, out);
}